// Round 18
// baseline (357.707 us; speedup 1.0000x reference)
//
#include <hip/hip_runtime.h>
#include <math.h>

#define N_NODES 50000
#define N_EDGES 800000
#define F_IN    64
#define H_DIM   128
#define N_GRAPH 512
#define NEG_SLOPE 0.2f
#define SCAN_NB ((N_NODES + 255) / 256)   // 196

typedef __attribute__((ext_vector_type(8))) short short8;   // 8 bf16 (4 VGPRs)
typedef __attribute__((ext_vector_type(4))) float f32x4;

// fp32 -> bf16(hi) + bf16(lo), truncation split (residual ~2^-16 relative)
__device__ __forceinline__ void bsplit(float v, unsigned short& h, unsigned short& l) {
    unsigned u = __float_as_uint(v);
    h = (unsigned short)(u >> 16);
    float hf = __uint_as_float(u & 0xFFFF0000u);
    float r = v - hf;
    l = (unsigned short)(__float_as_uint(r) >> 16);
}
__device__ __forceinline__ float bjoin(unsigned short h, unsigned short l) {
    return __uint_as_float(((unsigned)h) << 16) + __uint_as_float(((unsigned)l) << 16);
}

// ------------------- fused prep: prepX | prepW(frag-major swizzle) | dst-hist(+rank)
// W layout (per layer base): [kkblk][o][g][lane=quad*16+n16][j 0..7] —
// a wave's B-frag (16 cols x 8 k) is 64 contiguous 16B chunks, so the GEMM
// loads B straight from global coalesced (R8/R15 lesson: direct-global MFMA
// operands are fine iff fragment-major).
#define NB_PX 3125
#define NB_PW 192
#define NB_H  3125
__global__ __launch_bounds__(256) void k_prep(
    const float* __restrict__ x,
    const float* __restrict__ Wl1, const float* __restrict__ Wr1,
    const float* __restrict__ Wl2, const float* __restrict__ Wr2,
    const int* __restrict__ dst,
    unsigned short* __restrict__ Xhi, unsigned short* __restrict__ Xlo,
    unsigned short* __restrict__ WThi, unsigned short* __restrict__ WTlo,
    int* __restrict__ counts, int* __restrict__ rank)
{
    const int bid = blockIdx.x, tid = threadIdx.x;
    if (bid < NB_PX) {
        int i4 = (bid * 256 + tid) * 4;
        if (i4 < N_NODES * F_IN) {
            float4 v = *(const float4*)(x + i4);
            ushort4 h, l;
            bsplit(v.x, h.x, l.x); bsplit(v.y, h.y, l.y);
            bsplit(v.z, h.z, l.z); bsplit(v.w, h.w, l.w);
            *(ushort4*)(Xhi + i4) = h;
            *(ushort4*)(Xlo + i4) = l;
        }
    } else if (bid < NB_PX + NB_PW) {
        int idx = (bid - NB_PX) * 256 + tid;   // 0..49151
        if (idx < 49152) {
            const float* W; int K, li, base, o;
            if (idx < 8192)       { W = Wl1; K = 64;  li = idx;         base = 0;     o = 0; }
            else if (idx < 16384) { W = Wr1; K = 64;  li = idx - 8192;  base = 0;     o = 1; }
            else if (idx < 32768) { W = Wl2; K = 128; li = idx - 16384; base = 16384; o = 0; }
            else                  { W = Wr2; K = 128; li = idx - 32768; base = 16384; o = 1; }
            int c = li / K, k = li - c * K;
            int g = c >> 4, n16 = c & 15;
            int kkblk = k >> 5, quad = (k >> 3) & 3, j = k & 7;
            int off = base + kkblk * 8192 + o * 4096 + g * 512 + (quad * 16 + n16) * 8 + j;
            unsigned short h, l;
            bsplit(W[k * 128 + c], h, l);
            WThi[off] = h; WTlo[off] = l;
        }
    } else {
        int e = (bid - NB_PX - NB_PW) * 256 + tid;
        if (e < N_EDGES) {
            int pos = atomicAdd(&counts[dst[e]], 1);
            rank[e] = pos;
        }
    }
}

// ---------------------------------------------------------------- CSR scans
__global__ __launch_bounds__(256) void k_scan1(const int* __restrict__ counts,
                                               int* __restrict__ excl,
                                               int* __restrict__ partials) {
    __shared__ int s[256];
    int t = threadIdx.x, gid = blockIdx.x * 256 + t;
    int v = (gid < N_NODES) ? counts[gid] : 0;
    s[t] = v;
    __syncthreads();
    for (int off = 1; off < 256; off <<= 1) {
        int x = (t >= off) ? s[t - off] : 0;
        __syncthreads();
        s[t] += x;
        __syncthreads();
    }
    if (gid < N_NODES) excl[gid] = s[t] - v;
    if (t == 255) partials[blockIdx.x] = s[t];
}

__global__ __launch_bounds__(256) void k_scan3(int* __restrict__ offsets,
                                               const int* __restrict__ partials) {
    __shared__ int s[256];
    const int t = threadIdx.x, b = blockIdx.x;
    int v = (t < SCAN_NB) ? partials[t] : 0;
    s[t] = v;
    __syncthreads();
    for (int off = 1; off < 256; off <<= 1) {
        int x = (t >= off) ? s[t - off] : 0;
        __syncthreads();
        s[t] += x;
        __syncthreads();
    }
    int base = (b > 0) ? s[b - 1] : 0;
    int gid = b * 256 + t;
    if (gid < N_NODES) offsets[gid] += base;
    if (gid == 0) offsets[N_NODES] = N_EDGES;
}

// atomic-free CSR scatter (rank precomputed by k_prep's hist phase)
__global__ __launch_bounds__(256) void k_fill(const int* __restrict__ src,
                                              const int* __restrict__ dst,
                                              const int* __restrict__ offsets,
                                              const int* __restrict__ rank,
                                              int* __restrict__ col_src) {
    int e = blockIdx.x * 256 + threadIdx.x;
    if (e < N_EDGES) {
        col_src[offsets[dst[e]] + rank[e]] = src[e];
    }
}

// ---------------------------------------------------------------- MFMA GEMM
// R15-proven best: 3-pass bf16-split, 64-row blocks, per-kk staged X tile
// (2-barrier loop lets the compiler overlap next staging with MFMA — R16
// showed whole-K staging is a net loss), B-frags direct from the
// fragment-major swizzled W (coalesced 1KB/wave, L2-hot). LDS 10KB.
#define APITCH 40
#define GB_GEMM ((N_NODES + 63) / 64)   // 782
__global__ __launch_bounds__(256, 4) void k_gemm_mfma(
    const unsigned short* __restrict__ Xhi, const unsigned short* __restrict__ Xlo,
    const unsigned short* __restrict__ WThi, const unsigned short* __restrict__ WTlo,
    const float* __restrict__ bl, const float* __restrict__ br,
    float* __restrict__ OL, float* __restrict__ OR_, int K)
{
    __shared__ __align__(16) unsigned short Ah[64 * APITCH];
    __shared__ __align__(16) unsigned short Al[64 * APITCH];

    const int tid  = threadIdx.x;
    const int wv   = tid >> 6;        // wave: cols [wv*32, wv*32+32)
    const int lane = tid & 63;
    const int n16  = lane & 15;
    const int quad = lane >> 4;
    const int row0 = blockIdx.x * 64;

    f32x4 acc[4][2][2];               // [rtile][ctile][out]
#pragma unroll
    for (int r = 0; r < 4; ++r)
#pragma unroll
        for (int c = 0; c < 2; ++c)
#pragma unroll
            for (int o = 0; o < 2; ++o) acc[r][c][o] = (f32x4)0.f;

    for (int kk = 0; kk < K; kk += 32) {
        // stage X tile: 64 rows x 32 k, hi+lo. 512 chunks of 16B.
#pragma unroll
        for (int jj = 0; jj < 2; ++jj) {
            int j = tid + jj * 256;
            int part = j >> 8;
            int r = (j & 255) >> 2, sub = j & 3;
            int grow = row0 + r;
            const unsigned short* s = (part ? Xlo : Xhi) + (size_t)grow * K + kk + sub * 8;
            unsigned short* dl = (part ? Al : Ah) + r * APITCH + sub * 8;
            uint4 v = make_uint4(0u, 0u, 0u, 0u);
            if (grow < N_NODES) v = *(const uint4*)s;
            *(uint4*)dl = v;
        }
        __syncthreads();

        // B frags direct from swizzled global (coalesced: lane*8 shorts)
        const unsigned short* wb_h = WThi + (size_t)(kk >> 5) * 8192;
        const unsigned short* wb_l = WTlo + (size_t)(kk >> 5) * 8192;
        short8 bh[2][2], bo[2][2];
#pragma unroll
        for (int c = 0; c < 2; ++c)
#pragma unroll
            for (int o = 0; o < 2; ++o) {
                size_t off = (size_t)o * 4096 + (size_t)(wv * 2 + c) * 512 + (size_t)lane * 8;
                bh[c][o] = *(const short8*)(wb_h + off);
                bo[c][o] = *(const short8*)(wb_l + off);
            }
#pragma unroll
        for (int r = 0; r < 4; ++r) {
            int rl = r * 16 + n16;
            short8 ah = *(const short8*)(Ah + rl * APITCH + quad * 8);
            short8 al = *(const short8*)(Al + rl * APITCH + quad * 8);
#pragma unroll
            for (int c = 0; c < 2; ++c)
#pragma unroll
                for (int o = 0; o < 2; ++o) {
                    f32x4 t = acc[r][c][o];
                    t = __builtin_amdgcn_mfma_f32_16x16x32_bf16(ah, bh[c][o], t, 0, 0, 0);
                    t = __builtin_amdgcn_mfma_f32_16x16x32_bf16(ah, bo[c][o], t, 0, 0, 0);
                    t = __builtin_amdgcn_mfma_f32_16x16x32_bf16(al, bh[c][o], t, 0, 0, 0);
                    acc[r][c][o] = t;
                }
        }
        __syncthreads();
    }

    // epilogue: C/D layout col=lane&15, row=quad*4+reg
#pragma unroll
    for (int r = 0; r < 4; ++r)
#pragma unroll
        for (int c = 0; c < 2; ++c)
#pragma unroll
            for (int o = 0; o < 2; ++o) {
                int col = wv * 32 + c * 16 + n16;
                float bb = (o ? br : bl)[col];
                float* O = o ? OR_ : OL;
#pragma unroll
                for (int g = 0; g < 4; ++g) {
                    int grow = row0 + r * 16 + quad * 4 + g;
                    if (grow < N_NODES)
                        O[(size_t)grow * 128 + col] = acc[r][c][o][g] + bb;
                }
            }
}

// ---------------------------------------------------------------- edge phase
__device__ __forceinline__ float dot8_leaky(const float4& x0, const float4& x1,
                                            const float4& r0, const float4& r1,
                                            const float4& a0, const float4& a1) {
    float s = 0.f, e;
    e = x0.x + r0.x; s = fmaf(a0.x, (e > 0.f ? e : NEG_SLOPE * e), s);
    e = x0.y + r0.y; s = fmaf(a0.y, (e > 0.f ? e : NEG_SLOPE * e), s);
    e = x0.z + r0.z; s = fmaf(a0.z, (e > 0.f ? e : NEG_SLOPE * e), s);
    e = x0.w + r0.w; s = fmaf(a0.w, (e > 0.f ? e : NEG_SLOPE * e), s);
    e = x1.x + r1.x; s = fmaf(a1.x, (e > 0.f ? e : NEG_SLOPE * e), s);
    e = x1.y + r1.y; s = fmaf(a1.y, (e > 0.f ? e : NEG_SLOPE * e), s);
    e = x1.z + r1.z; s = fmaf(a1.z, (e > 0.f ? e : NEG_SLOPE * e), s);
    e = x1.w + r1.w; s = fmaf(a1.w, (e > 0.f ? e : NEG_SLOPE * e), s);
    return s;
}

// One wave per destination node; 4 quarters of 16 lanes each process a
// different incoming edge (R2-proven 28-VGPR structure — at its plateau
// across 5 attempted restructurings; do not touch).
// R11 lesson: never per-element global atomics (memory-side, 32B/atomic).
__global__ __launch_bounds__(256) void k_edge(
    const float* __restrict__ xl, const float* __restrict__ xr,
    const float* __restrict__ att, const float* __restrict__ bias,
    const int* __restrict__ offsets, const int* __restrict__ col_src,
    unsigned short* __restrict__ outHi, unsigned short* __restrict__ outLo)
{
    int d = blockIdx.x * 4 + (threadIdx.x >> 6);
    if (d >= N_NODES) return;
    const int lane = threadIdx.x & 63;
    const int q = lane >> 4;
    const int t = lane & 15;
    const size_t dim0 = (size_t)t * 8;

    const float4 r0 = *(const float4*)(xr + (size_t)d * 128 + dim0);
    const float4 r1 = *(const float4*)(xr + (size_t)d * 128 + dim0 + 4);
    const float4 a0 = *(const float4*)(att + dim0);
    const float4 a1 = *(const float4*)(att + dim0 + 4);

    const float4 xs0 = *(const float4*)(xl + (size_t)d * 128 + dim0);
    const float4 xs1 = *(const float4*)(xl + (size_t)d * 128 + dim0 + 4);
    float sl = dot8_leaky(xs0, xs1, r0, r1, a0, a1);
#pragma unroll
    for (int off = 1; off < 16; off <<= 1) sl += __shfl_xor(sl, off);

    float m, lsum;
    float4 acc0, acc1;
    if (q == 0) {
        m = sl; lsum = 1.f; acc0 = xs0; acc1 = xs1;
    } else {
        m = -INFINITY; lsum = 0.f;
        acc0 = make_float4(0.f, 0.f, 0.f, 0.f);
        acc1 = make_float4(0.f, 0.f, 0.f, 0.f);
    }

    const int ibeg = offsets[d], iend = offsets[d + 1];
    for (int base = ibeg; base < iend; base += 4) {
        int i = base + q;
        bool valid = (i < iend);
        int s = valid ? col_src[i] : d;
        const float4 x0 = *(const float4*)(xl + (size_t)s * 128 + dim0);
        const float4 x1 = *(const float4*)(xl + (size_t)s * 128 + dim0 + 4);
        float logit = dot8_leaky(x0, x1, r0, r1, a0, a1);
#pragma unroll
        for (int off = 1; off < 16; off <<= 1) logit += __shfl_xor(logit, off);
        if (valid) {
            float nm = fmaxf(m, logit);
            float sc = __expf(m - nm);
            float w  = __expf(logit - nm);
            lsum = lsum * sc + w;
            acc0.x = acc0.x * sc + w * x0.x;
            acc0.y = acc0.y * sc + w * x0.y;
            acc0.z = acc0.z * sc + w * x0.z;
            acc0.w = acc0.w * sc + w * x0.w;
            acc1.x = acc1.x * sc + w * x1.x;
            acc1.y = acc1.y * sc + w * x1.y;
            acc1.z = acc1.z * sc + w * x1.z;
            acc1.w = acc1.w * sc + w * x1.w;
            m = nm;
        }
    }

    float M = m;
    M = fmaxf(M, __shfl_xor(M, 16));
    M = fmaxf(M, __shfl_xor(M, 32));
    float sc = __expf(m - M);
    lsum *= sc;
    acc0.x *= sc; acc0.y *= sc; acc0.z *= sc; acc0.w *= sc;
    acc1.x *= sc; acc1.y *= sc; acc1.z *= sc; acc1.w *= sc;
#pragma unroll
    for (int off = 16; off <= 32; off <<= 1) {
        lsum  += __shfl_xor(lsum, off);
        acc0.x += __shfl_xor(acc0.x, off);
        acc0.y += __shfl_xor(acc0.y, off);
        acc0.z += __shfl_xor(acc0.z, off);
        acc0.w += __shfl_xor(acc0.w, off);
        acc1.x += __shfl_xor(acc1.x, off);
        acc1.y += __shfl_xor(acc1.y, off);
        acc1.z += __shfl_xor(acc1.z, off);
        acc1.w += __shfl_xor(acc1.w, off);
    }

    if (q == 0) {
        float inv = 1.f / lsum;
        const float4 b0 = *(const float4*)(bias + dim0);
        const float4 b1 = *(const float4*)(bias + dim0 + 4);
        float v[8];
        v[0] = fmaxf(fmaf(acc0.x, inv, b0.x), 0.f);
        v[1] = fmaxf(fmaf(acc0.y, inv, b0.y), 0.f);
        v[2] = fmaxf(fmaf(acc0.z, inv, b0.z), 0.f);
        v[3] = fmaxf(fmaf(acc0.w, inv, b0.w), 0.f);
        v[4] = fmaxf(fmaf(acc1.x, inv, b1.x), 0.f);
        v[5] = fmaxf(fmaf(acc1.y, inv, b1.y), 0.f);
        v[6] = fmaxf(fmaf(acc1.z, inv, b1.z), 0.f);
        v[7] = fmaxf(fmaf(acc1.w, inv, b1.w), 0.f);
        union { unsigned short s[8]; uint4 u; } H, L;
#pragma unroll
        for (int i = 0; i < 8; ++i) bsplit(v[i], H.s[i], L.s[i]);
        *(uint4*)(outHi + (size_t)d * 128 + dim0) = H.u;
        *(uint4*)(outLo + (size_t)d * 128 + dim0) = L.u;
    }
}

// ---------------------------------------------------------------- pooling
// R7-proven: 8 node-rows x 32 dim-groups, register run-length aggregation;
// pcnt counted via aggregated runs (tx==0 lanes only).
__global__ __launch_bounds__(256) void k_pool(
    const unsigned short* __restrict__ hHi, const unsigned short* __restrict__ hLo,
    const int* __restrict__ batch,
    float* __restrict__ psum, float* __restrict__ pcnt)
{
    const int tid = threadIdx.x;
    const int tx = tid & 31;
    const int ty = tid >> 5;
    const int n0 = blockIdx.x * 64;
    const int d0 = tx * 4;

    float4 acc = make_float4(0.f, 0.f, 0.f, 0.f);
    int cur = -1, crun = 0;
#pragma unroll
    for (int it = 0; it < 8; ++it) {
        int n = n0 + it * 8 + ty;
        if (n < N_NODES) {
            int g = batch[n];
            if (g != cur) {
                if (cur >= 0) {
                    atomicAdd(&psum[cur * 128 + d0 + 0], acc.x);
                    atomicAdd(&psum[cur * 128 + d0 + 1], acc.y);
                    atomicAdd(&psum[cur * 128 + d0 + 2], acc.z);
                    atomicAdd(&psum[cur * 128 + d0 + 3], acc.w);
                    if (tx == 0) atomicAdd(&pcnt[cur], (float)crun);
                }
                cur = g; acc = make_float4(0.f, 0.f, 0.f, 0.f); crun = 0;
            }
            ushort4 h = *(const ushort4*)(hHi + (size_t)n * 128 + d0);
            ushort4 l = *(const ushort4*)(hLo + (size_t)n * 128 + d0);
            acc.x += bjoin(h.x, l.x);
            acc.y += bjoin(h.y, l.y);
            acc.z += bjoin(h.z, l.z);
            acc.w += bjoin(h.w, l.w);
            crun++;
        }
    }
    if (cur >= 0) {
        atomicAdd(&psum[cur * 128 + d0 + 0], acc.x);
        atomicAdd(&psum[cur * 128 + d0 + 1], acc.y);
        atomicAdd(&psum[cur * 128 + d0 + 2], acc.z);
        atomicAdd(&psum[cur * 128 + d0 + 3], acc.w);
        if (tx == 0) atomicAdd(&pcnt[cur], (float)crun);
    }
}

// ---------------------------------------------------------------- head
__global__ __launch_bounds__(256) void k_head(
    const float* __restrict__ psum, const float* __restrict__ pcnt,
    const float* __restrict__ Wlin, const float* __restrict__ blin,
    float* __restrict__ out)
{
    int g = blockIdx.x * 4 + (threadIdx.x >> 6);
    if (g >= N_GRAPH) return;
    int lane = threadIdx.x & 63;
    float c = fmaxf(pcnt[g], 1.f);
    float2 s = *(const float2*)(psum + (size_t)g * 128 + lane * 2);
    float p = (s.x * Wlin[lane * 2] + s.y * Wlin[lane * 2 + 1]) / c;
#pragma unroll
    for (int off = 32; off > 0; off >>= 1) p += __shfl_xor(p, off);
    if (lane == 0) out[g] = p + blin[0];
}

// ---------------------------------------------------------------- launch
extern "C" void kernel_launch(void* const* d_in, const int* in_sizes, int n_in,
                              void* d_out, int out_size, void* d_ws, size_t ws_size,
                              hipStream_t stream) {
    const float* x     = (const float*)d_in[0];
    const int*   ei    = (const int*)d_in[1];
    const int*   batch = (const int*)d_in[3];
    const float* Wl1 = (const float*)d_in[4],  *bl1 = (const float*)d_in[5];
    const float* Wr1 = (const float*)d_in[6],  *br1 = (const float*)d_in[7];
    const float* att1= (const float*)d_in[8],  *b1  = (const float*)d_in[9];
    const float* Wl2 = (const float*)d_in[10], *bl2 = (const float*)d_in[11];
    const float* Wr2 = (const float*)d_in[12], *br2 = (const float*)d_in[13];
    const float* att2= (const float*)d_in[14], *b2  = (const float*)d_in[15];
    const float* Wlin= (const float*)d_in[16], *blin= (const float*)d_in[17];
    float* out = (float*)d_out;

    const int* src = ei;
    const int* dst = ei + N_EDGES;

    char* p = (char*)d_ws;
    auto carve = [&](size_t bytes) {
        void* r = (void*)p;
        p += (bytes + 255) & ~(size_t)255;
        return r;
    };
    float*          bufA   = (float*)carve((size_t)N_NODES * 128 * 4);
    float*          bufB   = (float*)carve((size_t)N_NODES * 128 * 4);
    unsigned short* Hhi    = (unsigned short*)carve((size_t)N_NODES * 128 * 2);
    unsigned short* Hlo    = (unsigned short*)carve((size_t)N_NODES * 128 * 2);
    unsigned short* Xhi1   = (unsigned short*)carve((size_t)N_NODES * 64 * 2);
    unsigned short* Xlo1   = (unsigned short*)carve((size_t)N_NODES * 64 * 2);
    unsigned short* WThi   = (unsigned short*)carve(49152 * 2);
    unsigned short* WTlo   = (unsigned short*)carve(49152 * 2);
    int*            offsets= (int*)carve((size_t)(N_NODES + 1) * 4);
    int*            rank   = (int*)carve((size_t)N_EDGES * 4);
    int*            partials=(int*)carve(256 * 4);
    int*            col_src= (int*)carve((size_t)N_EDGES * 4);
    // zero region: counts | psum | pcnt
    char* zb = (char*)carve(200192 + 262144 + 2048);
    int*   counts = (int*)zb;
    float* psum   = (float*)(zb + 200192);
    float* pcnt   = (float*)(zb + 200192 + 262144);
    const size_t zbytes = 200192 + 262144 + 2048;

    hipMemsetAsync(zb, 0, zbytes, stream);

    k_prep<<<NB_PX + NB_PW + NB_H, 256, 0, stream>>>(
        x, Wl1, Wr1, Wl2, Wr2, dst,
        Xhi1, Xlo1, WThi, WTlo, counts, rank);
    k_scan1<<<SCAN_NB, 256, 0, stream>>>(counts, offsets, partials);
    k_scan3<<<SCAN_NB, 256, 0, stream>>>(offsets, partials);
    k_fill <<<(N_EDGES + 255) / 256, 256, 0, stream>>>(src, dst, offsets, rank, col_src);

    // layer 1 (K=64)
    k_gemm_mfma<<<GB_GEMM, 256, 0, stream>>>(Xhi1, Xlo1, WThi, WTlo,
                                             bl1, br1, bufA, bufB, F_IN);
    k_edge<<<(N_NODES + 3) / 4, 256, 0, stream>>>(
        bufA, bufB, att1, b1, offsets, col_src, Hhi, Hlo);
    // layer 2 (K=128)
    k_gemm_mfma<<<GB_GEMM, 256, 0, stream>>>(Hhi, Hlo, WThi + 16384, WTlo + 16384,
                                             bl2, br2, bufA, bufB, H_DIM);
    k_edge<<<(N_NODES + 3) / 4, 256, 0, stream>>>(
        bufA, bufB, att2, b2, offsets, col_src, Hhi, Hlo);
    // pool + head
    k_pool<<<(N_NODES + 63) / 64, 256, 0, stream>>>(Hhi, Hlo, batch, psum, pcnt);
    k_head<<<(N_GRAPH + 3) / 4, 256, 0, stream>>>(psum, pcnt, Wlin, blin, out);
}

// Round 19
// 316.019 us; speedup vs baseline: 1.1319x; 1.1319x over previous
//
#include <hip/hip_runtime.h>
#include <hip/hip_fp16.h>
#include <math.h>

#define N_NODES 50000
#define N_EDGES 800000
#define F_IN    64
#define H_DIM   128
#define N_GRAPH 512
#define NEG_SLOPE 0.2f
#define SCAN_NB ((N_NODES + 255) / 256)   // 196

typedef __attribute__((ext_vector_type(8))) short short8;   // 8 bf16 (4 VGPRs)
typedef __attribute__((ext_vector_type(4))) float f32x4;

// fp32 -> bf16(hi) + bf16(lo), truncation split (residual ~2^-16 relative)
__device__ __forceinline__ void bsplit(float v, unsigned short& h, unsigned short& l) {
    unsigned u = __float_as_uint(v);
    h = (unsigned short)(u >> 16);
    float hf = __uint_as_float(u & 0xFFFF0000u);
    float r = v - hf;
    l = (unsigned short)(__float_as_uint(r) >> 16);
}
__device__ __forceinline__ float bjoin(unsigned short h, unsigned short l) {
    return __uint_as_float(((unsigned)h) << 16) + __uint_as_float(((unsigned)l) << 16);
}

// load 8 fp16 (16B) -> two float4
__device__ __forceinline__ void load_h8(const unsigned short* base, size_t off,
                                        float4& f0, float4& f1) {
    uint4 u = *(const uint4*)(base + off);
    float2 a = __half22float2(*(__half2*)&u.x);
    float2 b = __half22float2(*(__half2*)&u.y);
    float2 c = __half22float2(*(__half2*)&u.z);
    float2 d = __half22float2(*(__half2*)&u.w);
    f0 = make_float4(a.x, a.y, b.x, b.y);
    f1 = make_float4(c.x, c.y, d.x, d.y);
}

// ------------------- fused prep: prepX | prepW(frag-major swizzle) | dst-hist(+rank)
#define NB_PX 3125
#define NB_PW 192
#define NB_H  3125
__global__ __launch_bounds__(256) void k_prep(
    const float* __restrict__ x,
    const float* __restrict__ Wl1, const float* __restrict__ Wr1,
    const float* __restrict__ Wl2, const float* __restrict__ Wr2,
    const int* __restrict__ dst,
    unsigned short* __restrict__ Xhi, unsigned short* __restrict__ Xlo,
    unsigned short* __restrict__ WThi, unsigned short* __restrict__ WTlo,
    int* __restrict__ counts, int* __restrict__ rank)
{
    const int bid = blockIdx.x, tid = threadIdx.x;
    if (bid < NB_PX) {
        int i4 = (bid * 256 + tid) * 4;
        if (i4 < N_NODES * F_IN) {
            float4 v = *(const float4*)(x + i4);
            ushort4 h, l;
            bsplit(v.x, h.x, l.x); bsplit(v.y, h.y, l.y);
            bsplit(v.z, h.z, l.z); bsplit(v.w, h.w, l.w);
            *(ushort4*)(Xhi + i4) = h;
            *(ushort4*)(Xlo + i4) = l;
        }
    } else if (bid < NB_PX + NB_PW) {
        int idx = (bid - NB_PX) * 256 + tid;   // 0..49151
        if (idx < 49152) {
            const float* W; int K, li, base, o;
            if (idx < 8192)       { W = Wl1; K = 64;  li = idx;         base = 0;     o = 0; }
            else if (idx < 16384) { W = Wr1; K = 64;  li = idx - 8192;  base = 0;     o = 1; }
            else if (idx < 32768) { W = Wl2; K = 128; li = idx - 16384; base = 16384; o = 0; }
            else                  { W = Wr2; K = 128; li = idx - 32768; base = 16384; o = 1; }
            int c = li / K, k = li - c * K;
            int g = c >> 4, n16 = c & 15;
            int kkblk = k >> 5, quad = (k >> 3) & 3, j = k & 7;
            int off = base + kkblk * 8192 + o * 4096 + g * 512 + (quad * 16 + n16) * 8 + j;
            unsigned short h, l;
            bsplit(W[k * 128 + c], h, l);
            WThi[off] = h; WTlo[off] = l;
        }
    } else {
        int e = (bid - NB_PX - NB_PW) * 256 + tid;
        if (e < N_EDGES) {
            int pos = atomicAdd(&counts[dst[e]], 1);
            rank[e] = pos;
        }
    }
}

// ---------------------------------------------------------------- CSR scans
__global__ __launch_bounds__(256) void k_scan1(const int* __restrict__ counts,
                                               int* __restrict__ excl,
                                               int* __restrict__ partials) {
    __shared__ int s[256];
    int t = threadIdx.x, gid = blockIdx.x * 256 + t;
    int v = (gid < N_NODES) ? counts[gid] : 0;
    s[t] = v;
    __syncthreads();
    for (int off = 1; off < 256; off <<= 1) {
        int x = (t >= off) ? s[t - off] : 0;
        __syncthreads();
        s[t] += x;
        __syncthreads();
    }
    if (gid < N_NODES) excl[gid] = s[t] - v;
    if (t == 255) partials[blockIdx.x] = s[t];
}

__global__ __launch_bounds__(256) void k_scan3(int* __restrict__ offsets,
                                               const int* __restrict__ partials) {
    __shared__ int s[256];
    const int t = threadIdx.x, b = blockIdx.x;
    int v = (t < SCAN_NB) ? partials[t] : 0;
    s[t] = v;
    __syncthreads();
    for (int off = 1; off < 256; off <<= 1) {
        int x = (t >= off) ? s[t - off] : 0;
        __syncthreads();
        s[t] += x;
        __syncthreads();
    }
    int base = (b > 0) ? s[b - 1] : 0;
    int gid = b * 256 + t;
    if (gid < N_NODES) offsets[gid] += base;
    if (gid == 0) offsets[N_NODES] = N_EDGES;
}

// atomic-free CSR scatter (rank precomputed by k_prep's hist phase)
__global__ __launch_bounds__(256) void k_fill(const int* __restrict__ src,
                                              const int* __restrict__ dst,
                                              const int* __restrict__ offsets,
                                              const int* __restrict__ rank,
                                              int* __restrict__ col_src) {
    int e = blockIdx.x * 256 + threadIdx.x;
    if (e < N_EDGES) {
        col_src[offsets[dst[e]] + rank[e]] = src[e];
    }
}

// ---------------------------------------------------------------- MFMA GEMM
// R15-proven: 3-pass bf16-split, 64-row blocks, per-kk staged X tile,
// B-frags direct from fragment-major swizzled W. Output now FP16 (halves
// the edge kernel's gather traffic; fp16 rel-err 2^-11 keeps total absmax
// well under threshold).
#define APITCH 40
#define GB_GEMM ((N_NODES + 63) / 64)   // 782
__global__ __launch_bounds__(256, 4) void k_gemm_mfma(
    const unsigned short* __restrict__ Xhi, const unsigned short* __restrict__ Xlo,
    const unsigned short* __restrict__ WThi, const unsigned short* __restrict__ WTlo,
    const float* __restrict__ bl, const float* __restrict__ br,
    unsigned short* __restrict__ OL, unsigned short* __restrict__ OR_, int K)
{
    __shared__ __align__(16) unsigned short Ah[64 * APITCH];
    __shared__ __align__(16) unsigned short Al[64 * APITCH];

    const int tid  = threadIdx.x;
    const int wv   = tid >> 6;        // wave: cols [wv*32, wv*32+32)
    const int lane = tid & 63;
    const int n16  = lane & 15;
    const int quad = lane >> 4;
    const int row0 = blockIdx.x * 64;

    f32x4 acc[4][2][2];               // [rtile][ctile][out]
#pragma unroll
    for (int r = 0; r < 4; ++r)
#pragma unroll
        for (int c = 0; c < 2; ++c)
#pragma unroll
            for (int o = 0; o < 2; ++o) acc[r][c][o] = (f32x4)0.f;

    for (int kk = 0; kk < K; kk += 32) {
        // stage X tile: 64 rows x 32 k, hi+lo. 512 chunks of 16B.
#pragma unroll
        for (int jj = 0; jj < 2; ++jj) {
            int j = tid + jj * 256;
            int part = j >> 8;
            int r = (j & 255) >> 2, sub = j & 3;
            int grow = row0 + r;
            const unsigned short* s = (part ? Xlo : Xhi) + (size_t)grow * K + kk + sub * 8;
            unsigned short* dl = (part ? Al : Ah) + r * APITCH + sub * 8;
            uint4 v = make_uint4(0u, 0u, 0u, 0u);
            if (grow < N_NODES) v = *(const uint4*)s;
            *(uint4*)dl = v;
        }
        __syncthreads();

        // B frags direct from swizzled global (coalesced: lane*8 shorts)
        const unsigned short* wb_h = WThi + (size_t)(kk >> 5) * 8192;
        const unsigned short* wb_l = WTlo + (size_t)(kk >> 5) * 8192;
        short8 bh[2][2], bo[2][2];
#pragma unroll
        for (int c = 0; c < 2; ++c)
#pragma unroll
            for (int o = 0; o < 2; ++o) {
                size_t off = (size_t)o * 4096 + (size_t)(wv * 2 + c) * 512 + (size_t)lane * 8;
                bh[c][o] = *(const short8*)(wb_h + off);
                bo[c][o] = *(const short8*)(wb_l + off);
            }
#pragma unroll
        for (int r = 0; r < 4; ++r) {
            int rl = r * 16 + n16;
            short8 ah = *(const short8*)(Ah + rl * APITCH + quad * 8);
            short8 al = *(const short8*)(Al + rl * APITCH + quad * 8);
#pragma unroll
            for (int c = 0; c < 2; ++c)
#pragma unroll
                for (int o = 0; o < 2; ++o) {
                    f32x4 t = acc[r][c][o];
                    t = __builtin_amdgcn_mfma_f32_16x16x32_bf16(ah, bh[c][o], t, 0, 0, 0);
                    t = __builtin_amdgcn_mfma_f32_16x16x32_bf16(ah, bo[c][o], t, 0, 0, 0);
                    t = __builtin_amdgcn_mfma_f32_16x16x32_bf16(al, bh[c][o], t, 0, 0, 0);
                    acc[r][c][o] = t;
                }
        }
        __syncthreads();
    }

    // epilogue: C/D layout col=lane&15, row=quad*4+reg; store fp16
#pragma unroll
    for (int r = 0; r < 4; ++r)
#pragma unroll
        for (int c = 0; c < 2; ++c)
#pragma unroll
            for (int o = 0; o < 2; ++o) {
                int col = wv * 32 + c * 16 + n16;
                float bb = (o ? br : bl)[col];
                unsigned short* O = o ? OR_ : OL;
#pragma unroll
                for (int g = 0; g < 4; ++g) {
                    int grow = row0 + r * 16 + quad * 4 + g;
                    if (grow < N_NODES) {
                        __half hv = __float2half(acc[r][c][o][g] + bb);
                        O[(size_t)grow * 128 + col] = *(unsigned short*)&hv;
                    }
                }
            }
}

// ---------------------------------------------------------------- edge phase
__device__ __forceinline__ float dot8_leaky(const float4& x0, const float4& x1,
                                            const float4& r0, const float4& r1,
                                            const float4& a0, const float4& a1) {
    float s = 0.f, e;
    e = x0.x + r0.x; s = fmaf(a0.x, (e > 0.f ? e : NEG_SLOPE * e), s);
    e = x0.y + r0.y; s = fmaf(a0.y, (e > 0.f ? e : NEG_SLOPE * e), s);
    e = x0.z + r0.z; s = fmaf(a0.z, (e > 0.f ? e : NEG_SLOPE * e), s);
    e = x0.w + r0.w; s = fmaf(a0.w, (e > 0.f ? e : NEG_SLOPE * e), s);
    e = x1.x + r1.x; s = fmaf(a1.x, (e > 0.f ? e : NEG_SLOPE * e), s);
    e = x1.y + r1.y; s = fmaf(a1.y, (e > 0.f ? e : NEG_SLOPE * e), s);
    e = x1.z + r1.z; s = fmaf(a1.z, (e > 0.f ? e : NEG_SLOPE * e), s);
    e = x1.w + r1.w; s = fmaf(a1.w, (e > 0.f ? e : NEG_SLOPE * e), s);
    return s;
}

// One wave per destination node; 4 quarters of 16 lanes each process a
// different incoming edge (R2-proven structure). Rows now FP16: one uint4
// load per lane per row (was 2x float4) -> 2x traffic cut + 2x edges in
// flight at fixed MLP capacity (the measured limiter).
__global__ __launch_bounds__(256) void k_edge(
    const unsigned short* __restrict__ xl, const unsigned short* __restrict__ xr,
    const float* __restrict__ att, const float* __restrict__ bias,
    const int* __restrict__ offsets, const int* __restrict__ col_src,
    unsigned short* __restrict__ outHi, unsigned short* __restrict__ outLo)
{
    int d = blockIdx.x * 4 + (threadIdx.x >> 6);
    if (d >= N_NODES) return;
    const int lane = threadIdx.x & 63;
    const int q = lane >> 4;
    const int t = lane & 15;
    const size_t dim0 = (size_t)t * 8;

    float4 r0, r1;
    load_h8(xr, (size_t)d * 128 + dim0, r0, r1);
    const float4 a0 = *(const float4*)(att + dim0);
    const float4 a1 = *(const float4*)(att + dim0 + 4);

    float4 xs0, xs1;
    load_h8(xl, (size_t)d * 128 + dim0, xs0, xs1);
    float sl = dot8_leaky(xs0, xs1, r0, r1, a0, a1);
#pragma unroll
    for (int off = 1; off < 16; off <<= 1) sl += __shfl_xor(sl, off);

    float m, lsum;
    float4 acc0, acc1;
    if (q == 0) {
        m = sl; lsum = 1.f; acc0 = xs0; acc1 = xs1;
    } else {
        m = -INFINITY; lsum = 0.f;
        acc0 = make_float4(0.f, 0.f, 0.f, 0.f);
        acc1 = make_float4(0.f, 0.f, 0.f, 0.f);
    }

    const int ibeg = offsets[d], iend = offsets[d + 1];
    for (int base = ibeg; base < iend; base += 4) {
        int i = base + q;
        bool valid = (i < iend);
        int s = valid ? col_src[i] : d;
        float4 x0, x1;
        load_h8(xl, (size_t)s * 128 + dim0, x0, x1);
        float logit = dot8_leaky(x0, x1, r0, r1, a0, a1);
#pragma unroll
        for (int off = 1; off < 16; off <<= 1) logit += __shfl_xor(logit, off);
        if (valid) {
            float nm = fmaxf(m, logit);
            float sc = __expf(m - nm);
            float w  = __expf(logit - nm);
            lsum = lsum * sc + w;
            acc0.x = acc0.x * sc + w * x0.x;
            acc0.y = acc0.y * sc + w * x0.y;
            acc0.z = acc0.z * sc + w * x0.z;
            acc0.w = acc0.w * sc + w * x0.w;
            acc1.x = acc1.x * sc + w * x1.x;
            acc1.y = acc1.y * sc + w * x1.y;
            acc1.z = acc1.z * sc + w * x1.z;
            acc1.w = acc1.w * sc + w * x1.w;
            m = nm;
        }
    }

    float M = m;
    M = fmaxf(M, __shfl_xor(M, 16));
    M = fmaxf(M, __shfl_xor(M, 32));
    float sc = __expf(m - M);
    lsum *= sc;
    acc0.x *= sc; acc0.y *= sc; acc0.z *= sc; acc0.w *= sc;
    acc1.x *= sc; acc1.y *= sc; acc1.z *= sc; acc1.w *= sc;
#pragma unroll
    for (int off = 16; off <= 32; off <<= 1) {
        lsum  += __shfl_xor(lsum, off);
        acc0.x += __shfl_xor(acc0.x, off);
        acc0.y += __shfl_xor(acc0.y, off);
        acc0.z += __shfl_xor(acc0.z, off);
        acc0.w += __shfl_xor(acc0.w, off);
        acc1.x += __shfl_xor(acc1.x, off);
        acc1.y += __shfl_xor(acc1.y, off);
        acc1.z += __shfl_xor(acc1.z, off);
        acc1.w += __shfl_xor(acc1.w, off);
    }

    if (q == 0) {
        float inv = 1.f / lsum;
        const float4 b0 = *(const float4*)(bias + dim0);
        const float4 b1 = *(const float4*)(bias + dim0 + 4);
        float v[8];
        v[0] = fmaxf(fmaf(acc0.x, inv, b0.x), 0.f);
        v[1] = fmaxf(fmaf(acc0.y, inv, b0.y), 0.f);
        v[2] = fmaxf(fmaf(acc0.z, inv, b0.z), 0.f);
        v[3] = fmaxf(fmaf(acc0.w, inv, b0.w), 0.f);
        v[4] = fmaxf(fmaf(acc1.x, inv, b1.x), 0.f);
        v[5] = fmaxf(fmaf(acc1.y, inv, b1.y), 0.f);
        v[6] = fmaxf(fmaf(acc1.z, inv, b1.z), 0.f);
        v[7] = fmaxf(fmaf(acc1.w, inv, b1.w), 0.f);
        union { unsigned short s[8]; uint4 u; } H, L;
#pragma unroll
        for (int i = 0; i < 8; ++i) bsplit(v[i], H.s[i], L.s[i]);
        *(uint4*)(outHi + (size_t)d * 128 + dim0) = H.u;
        *(uint4*)(outLo + (size_t)d * 128 + dim0) = L.u;
    }
}

// ---------------------------------------------------------------- pooling
__global__ __launch_bounds__(256) void k_pool(
    const unsigned short* __restrict__ hHi, const unsigned short* __restrict__ hLo,
    const int* __restrict__ batch,
    float* __restrict__ psum, float* __restrict__ pcnt)
{
    const int tid = threadIdx.x;
    const int tx = tid & 31;
    const int ty = tid >> 5;
    const int n0 = blockIdx.x * 64;
    const int d0 = tx * 4;

    float4 acc = make_float4(0.f, 0.f, 0.f, 0.f);
    int cur = -1, crun = 0;
#pragma unroll
    for (int it = 0; it < 8; ++it) {
        int n = n0 + it * 8 + ty;
        if (n < N_NODES) {
            int g = batch[n];
            if (g != cur) {
                if (cur >= 0) {
                    atomicAdd(&psum[cur * 128 + d0 + 0], acc.x);
                    atomicAdd(&psum[cur * 128 + d0 + 1], acc.y);
                    atomicAdd(&psum[cur * 128 + d0 + 2], acc.z);
                    atomicAdd(&psum[cur * 128 + d0 + 3], acc.w);
                    if (tx == 0) atomicAdd(&pcnt[cur], (float)crun);
                }
                cur = g; acc = make_float4(0.f, 0.f, 0.f, 0.f); crun = 0;
            }
            ushort4 h = *(const ushort4*)(hHi + (size_t)n * 128 + d0);
            ushort4 l = *(const ushort4*)(hLo + (size_t)n * 128 + d0);
            acc.x += bjoin(h.x, l.x);
            acc.y += bjoin(h.y, l.y);
            acc.z += bjoin(h.z, l.z);
            acc.w += bjoin(h.w, l.w);
            crun++;
        }
    }
    if (cur >= 0) {
        atomicAdd(&psum[cur * 128 + d0 + 0], acc.x);
        atomicAdd(&psum[cur * 128 + d0 + 1], acc.y);
        atomicAdd(&psum[cur * 128 + d0 + 2], acc.z);
        atomicAdd(&psum[cur * 128 + d0 + 3], acc.w);
        if (tx == 0) atomicAdd(&pcnt[cur], (float)crun);
    }
}

// ---------------------------------------------------------------- head
__global__ __launch_bounds__(256) void k_head(
    const float* __restrict__ psum, const float* __restrict__ pcnt,
    const float* __restrict__ Wlin, const float* __restrict__ blin,
    float* __restrict__ out)
{
    int g = blockIdx.x * 4 + (threadIdx.x >> 6);
    if (g >= N_GRAPH) return;
    int lane = threadIdx.x & 63;
    float c = fmaxf(pcnt[g], 1.f);
    float2 s = *(const float2*)(psum + (size_t)g * 128 + lane * 2);
    float p = (s.x * Wlin[lane * 2] + s.y * Wlin[lane * 2 + 1]) / c;
#pragma unroll
    for (int off = 32; off > 0; off >>= 1) p += __shfl_xor(p, off);
    if (lane == 0) out[g] = p + blin[0];
}

// ---------------------------------------------------------------- launch
extern "C" void kernel_launch(void* const* d_in, const int* in_sizes, int n_in,
                              void* d_out, int out_size, void* d_ws, size_t ws_size,
                              hipStream_t stream) {
    const float* x     = (const float*)d_in[0];
    const int*   ei    = (const int*)d_in[1];
    const int*   batch = (const int*)d_in[3];
    const float* Wl1 = (const float*)d_in[4],  *bl1 = (const float*)d_in[5];
    const float* Wr1 = (const float*)d_in[6],  *br1 = (const float*)d_in[7];
    const float* att1= (const float*)d_in[8],  *b1  = (const float*)d_in[9];
    const float* Wl2 = (const float*)d_in[10], *bl2 = (const float*)d_in[11];
    const float* Wr2 = (const float*)d_in[12], *br2 = (const float*)d_in[13];
    const float* att2= (const float*)d_in[14], *b2  = (const float*)d_in[15];
    const float* Wlin= (const float*)d_in[16], *blin= (const float*)d_in[17];
    float* out = (float*)d_out;

    const int* src = ei;
    const int* dst = ei + N_EDGES;

    char* p = (char*)d_ws;
    auto carve = [&](size_t bytes) {
        void* r = (void*)p;
        p += (bytes + 255) & ~(size_t)255;
        return r;
    };
    unsigned short* bufA   = (unsigned short*)carve((size_t)N_NODES * 128 * 2); // xl fp16
    unsigned short* bufB   = (unsigned short*)carve((size_t)N_NODES * 128 * 2); // xr fp16
    unsigned short* Hhi    = (unsigned short*)carve((size_t)N_NODES * 128 * 2);
    unsigned short* Hlo    = (unsigned short*)carve((size_t)N_NODES * 128 * 2);
    unsigned short* Xhi1   = (unsigned short*)carve((size_t)N_NODES * 64 * 2);
    unsigned short* Xlo1   = (unsigned short*)carve((size_t)N_NODES * 64 * 2);
    unsigned short* WThi   = (unsigned short*)carve(49152 * 2);
    unsigned short* WTlo   = (unsigned short*)carve(49152 * 2);
    int*            offsets= (int*)carve((size_t)(N_NODES + 1) * 4);
    int*            rank   = (int*)carve((size_t)N_EDGES * 4);
    int*            partials=(int*)carve(256 * 4);
    int*            col_src= (int*)carve((size_t)N_EDGES * 4);
    // zero region: counts | psum | pcnt
    char* zb = (char*)carve(200192 + 262144 + 2048);
    int*   counts = (int*)zb;
    float* psum   = (float*)(zb + 200192);
    float* pcnt   = (float*)(zb + 200192 + 262144);
    const size_t zbytes = 200192 + 262144 + 2048;

    hipMemsetAsync(zb, 0, zbytes, stream);

    k_prep<<<NB_PX + NB_PW + NB_H, 256, 0, stream>>>(
        x, Wl1, Wr1, Wl2, Wr2, dst,
        Xhi1, Xlo1, WThi, WTlo, counts, rank);
    k_scan1<<<SCAN_NB, 256, 0, stream>>>(counts, offsets, partials);
    k_scan3<<<SCAN_NB, 256, 0, stream>>>(offsets, partials);
    k_fill <<<(N_EDGES + 255) / 256, 256, 0, stream>>>(src, dst, offsets, rank, col_src);

    // layer 1 (K=64)
    k_gemm_mfma<<<GB_GEMM, 256, 0, stream>>>(Xhi1, Xlo1, WThi, WTlo,
                                             bl1, br1, bufA, bufB, F_IN);
    k_edge<<<(N_NODES + 3) / 4, 256, 0, stream>>>(
        bufA, bufB, att1, b1, offsets, col_src, Hhi, Hlo);
    // layer 2 (K=128)
    k_gemm_mfma<<<GB_GEMM, 256, 0, stream>>>(Hhi, Hlo, WThi + 16384, WTlo + 16384,
                                             bl2, br2, bufA, bufB, H_DIM);
    k_edge<<<(N_NODES + 3) / 4, 256, 0, stream>>>(
        bufA, bufB, att2, b2, offsets, col_src, Hhi, Hlo);
    // pool + head
    k_pool<<<(N_NODES + 63) / 64, 256, 0, stream>>>(Hhi, Hlo, batch, psum, pcnt);
    k_head<<<(N_GRAPH + 3) / 4, 256, 0, stream>>>(psum, pcnt, Wlin, blin, out);
}